// Round 3
// baseline (470.240 us; speedup 1.0000x reference)
//
#include <hip/hip_runtime.h>
#include <math.h>

// GeometricEmbedding pair-once kernel. B=4, N=M=3000, d_model=2, sigma_d=1.
// d[b,n,m] = sqrt(max(2 - 2*<p0[b,n],p1[b,m]>, 0))
// p0_emb[b,n] = p0[b,n] * (sum_m sin(d), sum_m cos(d))
// p1_emb[b,m] = p1[b,m] * (sum_n sin(d), sum_n cos(d))
//
// R2 post-mortem: two-sided version latency-bound at 40us (VALUBusy 57%).
// This version computes each pair ONCE (36M evals, not 72M): row sums in
// registers, col sums via lane-staggered LDS ds_add_f32 (conflict-free),
// partials combined through global f32 atomics into d_ws, tiny epilogue.

#define GB 4
#define GN 3000
#define GM 3000
#define TN 256                    // rows per block (1 thread : 1 row n)
#define TM 64                     // partner chunk per block
#define NT ((GN + TN - 1) / TN)   // 12 n-tiles
#define MC ((GM + TM - 1) / TM)   // 47 m-chunks
#define INV2PI 0.15915494309189535f

// d_ws layout (floats): ws_row[GB][GN][2] | ws_col[GB][GM][2]  = 48000 floats
#define WS_FLOATS (2 * GB * GN * 2)

__global__ __launch_bounds__(256) void geo_pair_kernel(
    const float* __restrict__ p0,
    const float* __restrict__ p1,
    float* __restrict__ ws)
{
    __shared__ float qx[TM];
    __shared__ float qy[TM];
    __shared__ float lds_s[TM];
    __shared__ float lds_c[TM];

    const int t = threadIdx.x;
    int id = blockIdx.x;
    const int mc = id % MC;
    id /= MC;
    const int ntile = id % NT;
    const int b = id / NT;

    const int m0 = mc * TM;
    const int mcount = (GM - m0 < TM) ? (GM - m0) : TM;   // 56 on last chunk

    if (t < TM) {
        int m = m0 + ((t < mcount) ? t : (mcount - 1));   // clamp (unused lanes)
        float2 q = ((const float2*)p1)[b * GM + m];
        qx[t] = q.x;
        qy[t] = q.y;
        lds_s[t] = 0.0f;
        lds_c[t] = 0.0f;
    }
    __syncthreads();

    const int n = ntile * TN + t;
    if (n < GN) {
        const float2 pr = ((const float2*)p0)[b * GN + n];
        const float px = pr.x, py = pr.y;
        float sA = 0.0f, cA = 0.0f;

        if (mcount == TM) {
            #pragma unroll 4
            for (int j = 0; j < TM; ++j) {
                const int mi = (j + t) & (TM - 1);        // lane-staggered
                float dot = fmaf(px, qx[mi], py * qy[mi]);
                float tt  = fmaxf(fmaf(-2.0f, dot, 2.0f), 0.0f);
                float d   = __builtin_amdgcn_sqrtf(tt);
                float r   = d * INV2PI;
                float s   = __builtin_amdgcn_sinf(r);     // v_sin_f32
                float c   = __builtin_amdgcn_cosf(r);     // v_cos_f32
                sA += s;
                cA += c;
                atomicAdd(&lds_s[mi], s);                 // ds_add_f32, 2-way free
                atomicAdd(&lds_c[mi], c);
            }
        } else {
            for (int j = 0; j < TM; ++j) {
                const int mi = (j + t) & (TM - 1);
                if (mi < mcount) {
                    float dot = fmaf(px, qx[mi], py * qy[mi]);
                    float tt  = fmaxf(fmaf(-2.0f, dot, 2.0f), 0.0f);
                    float d   = __builtin_amdgcn_sqrtf(tt);
                    float r   = d * INV2PI;
                    float s   = __builtin_amdgcn_sinf(r);
                    float c   = __builtin_amdgcn_cosf(r);
                    sA += s;
                    cA += c;
                    atomicAdd(&lds_s[mi], s);
                    atomicAdd(&lds_c[mi], c);
                }
            }
        }

        // row partial -> global accumulator (native global_atomic_add_f32)
        unsafeAtomicAdd(&ws[(b * GN + n) * 2 + 0], sA);
        unsafeAtomicAdd(&ws[(b * GN + n) * 2 + 1], cA);
    }

    __syncthreads();

    if (t < mcount) {
        unsafeAtomicAdd(&ws[(GB * GN + b * GM + m0 + t) * 2 + 0], lds_s[t]);
        unsafeAtomicAdd(&ws[(GB * GN + b * GM + m0 + t) * 2 + 1], lds_c[t]);
    }
}

// out[0..12000) float2 = p0 * ws_row ; out[12000..24000) float2 = p1 * ws_col
__global__ __launch_bounds__(256) void geo_epilogue_kernel(
    const float* __restrict__ p0,
    const float* __restrict__ p1,
    const float* __restrict__ ws,
    float* __restrict__ out)
{
    const int i = blockIdx.x * 256 + threadIdx.x;   // row index over both sides
    const int ROWS = GB * GN;                       // 12000 per side
    if (i >= 2 * ROWS) return;
    const float2 pr = (i < ROWS) ? ((const float2*)p0)[i]
                                 : ((const float2*)p1)[i - ROWS];
    const float2 w = ((const float2*)ws)[i];
    float2 res;
    res.x = pr.x * w.x;
    res.y = pr.y * w.y;
    ((float2*)out)[i] = res;
}

extern "C" void kernel_launch(void* const* d_in, const int* in_sizes, int n_in,
                              void* d_out, int out_size, void* d_ws, size_t ws_size,
                              hipStream_t stream) {
    const float* points0 = (const float*)d_in[0];
    const float* points1 = (const float*)d_in[1];
    float* out = (float*)d_out;
    float* ws = (float*)d_ws;

    hipMemsetAsync(ws, 0, WS_FLOATS * sizeof(float), stream);

    dim3 grid(GB * NT * MC);      // 4 * 12 * 47 = 2256
    geo_pair_kernel<<<grid, dim3(256), 0, stream>>>(points0, points1, ws);

    const int rows2 = 2 * GB * GN;                    // 24000
    geo_epilogue_kernel<<<dim3((rows2 + 255) / 256), dim3(256), 0, stream>>>(
        points0, points1, ws, out);
}

// Round 4
// 85.189 us; speedup vs baseline: 5.5199x; 5.5199x over previous
//
#include <hip/hip_runtime.h>
#include <math.h>

// GeometricEmbedding pair-once, register-rotation kernel. B=4, N=M=3000.
// d[b,n,m] = sqrt(max(2 - 2*<p0[b,n],p1[b,m]>, 0))
// p0_emb[b,n] = p0[b,n] * (sum_m sin d, sum_m cos d)
// p1_emb[b,m] = p1[b,m] * (sum_n sin d, sum_n cos d)
//
// R3 post-mortem: LDS atomicAdd(float) = CAS retry loop -> 424us, VALUBusy 3%.
// This version: one wave per 64x64 tile. Lane l owns row rbase+l (stationary
// register rowsum) and a rotating column slot: (qx,qy,colsin,colcos) rotate
// lane->lane-1 each step via ds_bpermute with a FIXED address. 64 steps visit
// all 64x64 pairs exactly once; after 64 rotations colacc is home at lane l.
// No LDS, no atomics in the loop. Tile partials -> global f32 atomics (native
// unsafeAtomicAdd), tiny epilogue multiplies by point coords.

#define GB 4
#define GN 3000          // == M
#define NT 47            // ceil(3000/64) tiles per side
#define TPB (NT * NT)    // 2209 tiles per batch
#define INV2PI 0.15915494309189535f

// ws layout (floats): ws_row[GB][GN][2] | ws_col[GB][GN][2] = 48000 floats
#define WS_FLOATS (2 * GB * GN * 2)

__device__ __forceinline__ float bperm(int addr, float x) {
    return __int_as_float(__builtin_amdgcn_ds_bpermute(addr, __float_as_int(x)));
}

__global__ __launch_bounds__(256) void geo_tile_kernel(
    const float* __restrict__ p0,
    const float* __restrict__ p1,
    float* __restrict__ ws)
{
    const int lane = threadIdx.x & 63;
    const int wid  = (blockIdx.x << 2) | (threadIdx.x >> 6);   // 0..8835

    int b   = wid / TPB;                 // magic-mul
    int rem = wid - b * TPB;
    int rt  = rem / NT;
    int ct  = rem - rt * NT;

    const int rbase = rt << 6;
    const int cbase = ct << 6;

    int rl = rbase + lane; if (rl >= GN) rl = GN - 1;   // clamped load idx
    int cl = cbase + lane; if (cl >= GN) cl = GN - 1;

    const float2 pr = ((const float2*)p0)[b * GN + rl];
    const float2 qq = ((const float2*)p1)[b * GN + cl];
    const float px = pr.x, py = pr.y;
    float qx = qq.x, qy = qq.y;

    const int perm = ((lane + 1) & 63) << 2;   // fixed rotation address

    float rs = 0.f, rc = 0.f;   // row accumulator (stationary)
    float cs = 0.f, cc = 0.f;   // column accumulator (rotates with q)

    const bool full = (rbase + 64 <= GN) && (cbase + 64 <= GN);

    if (full) {
        #pragma unroll 8
        for (int j = 0; j < 64; ++j) {
            float dot = fmaf(px, qx, py * qy);
            float t   = fmaxf(fmaf(-2.0f, dot, 2.0f), 0.0f);
            float d   = __builtin_amdgcn_sqrtf(t);
            float r   = d * INV2PI;
            float s   = __builtin_amdgcn_sinf(r);
            float c   = __builtin_amdgcn_cosf(r);
            rs += s;  rc += c;
            cs += s;  cc += c;
            qx = bperm(perm, qx);
            qy = bperm(perm, qy);
            cs = bperm(perm, cs);
            cc = bperm(perm, cc);
        }
    } else {
        const float rowv = (rbase + lane < GN) ? 1.0f : 0.0f;
        float colv = (cbase + lane < GN) ? 1.0f : 0.0f;   // rotates with q
        #pragma unroll 4
        for (int j = 0; j < 64; ++j) {
            float dot = fmaf(px, qx, py * qy);
            float t   = fmaxf(fmaf(-2.0f, dot, 2.0f), 0.0f);
            float d   = __builtin_amdgcn_sqrtf(t);
            float r   = d * INV2PI;
            float s   = __builtin_amdgcn_sinf(r) * rowv;  // dead rows give 0
            float c   = __builtin_amdgcn_cosf(r) * rowv;
            rs = fmaf(s, colv, rs);                       // dead cols give 0
            rc = fmaf(c, colv, rc);
            cs += s;  cc += c;
            qx = bperm(perm, qx);
            qy = bperm(perm, qy);
            cs = bperm(perm, cs);
            cc = bperm(perm, cc);
            colv = bperm(perm, colv);
        }
    }

    if (rbase + lane < GN) {
        float* wr = ws + (b * GN + rbase + lane) * 2;
        unsafeAtomicAdd(wr + 0, rs);
        unsafeAtomicAdd(wr + 1, rc);
    }
    if (cbase + lane < GN) {
        float* wc = ws + (GB * GN + b * GN + cbase + lane) * 2;
        unsafeAtomicAdd(wc + 0, cs);
        unsafeAtomicAdd(wc + 1, cc);
    }
}

// out[0..12000) float2 = p0 * ws_row ; out[12000..24000) float2 = p1 * ws_col
__global__ __launch_bounds__(256) void geo_epilogue_kernel(
    const float* __restrict__ p0,
    const float* __restrict__ p1,
    const float* __restrict__ ws,
    float* __restrict__ out)
{
    const int i = blockIdx.x * 256 + threadIdx.x;
    const int ROWS = GB * GN;                       // 12000 per side
    if (i >= 2 * ROWS) return;
    const float2 pr = (i < ROWS) ? ((const float2*)p0)[i]
                                 : ((const float2*)p1)[i - ROWS];
    const float2 w = ((const float2*)ws)[i];
    float2 res;
    res.x = pr.x * w.x;
    res.y = pr.y * w.y;
    ((float2*)out)[i] = res;
}

extern "C" void kernel_launch(void* const* d_in, const int* in_sizes, int n_in,
                              void* d_out, int out_size, void* d_ws, size_t ws_size,
                              hipStream_t stream) {
    const float* points0 = (const float*)d_in[0];
    const float* points1 = (const float*)d_in[1];
    float* out = (float*)d_out;
    float* ws = (float*)d_ws;

    hipMemsetAsync(ws, 0, WS_FLOATS * sizeof(float), stream);

    const int nblocks = (GB * TPB) / 4 + ((GB * TPB) % 4 ? 1 : 0);  // 2209
    geo_tile_kernel<<<dim3(nblocks), dim3(256), 0, stream>>>(points0, points1, ws);

    const int rows2 = 2 * GB * GN;                  // 24000
    geo_epilogue_kernel<<<dim3((rows2 + 255) / 256), dim3(256), 0, stream>>>(
        points0, points1, ws, out);
}

// Round 5
// 84.202 us; speedup vs baseline: 5.5847x; 1.0117x over previous
//
#include <hip/hip_runtime.h>
#include <math.h>

// GeometricEmbedding pair-once, DPP-rotation kernel. B=4, N=M=3000.
// d[b,n,m] = sqrt(max(2 - 2*<p0[b,n],p1[b,m]>, 0))
// p0_emb[b,n] = p0[b,n] * (sum_m sin d, sum_m cos d)
// p1_emb[b,m] = p1[b,m] * (sum_n sin d, sum_n cos d)
//
// R4 post-mortem: ds_bpermute rotation saturated the per-CU LDS pipe
// (4 DS/pair-step x 4 SIMDs >> DS throughput). This version rotates with
// v_mov_b32_dpp row_ror:1 (full-rate VALU, no LDS pipe at all):
//   wave tile = 64 rows x 64 cols, processed as 4 groups of 16 cols.
//   Lane l owns row rt*64+l. Within a group, (qx,qy,colsin,colcos) rotate
//   through the 16-lane DPP row each step; after 16 steps they're home.
//   Col partials reduced across the 4 row-groups via 2 shfl_xor per var.
// No atomics: partials land in disjoint ws slots, fused reduce+epilogue
// kernel sums 47 tile-partials per output row. Fully deterministic.

#define GB 4
#define GN 3000
#define NT 47                 // tiles per side (64 wide)
#define PAD 3008              // 47*64, padded row/col index space
#define TPB (NT * NT)         // 2209 tiles per batch
#define INV2PI 0.15915494309189535f

// ws layout (float2):
//   ws_row[(b*NT + ct)*PAD + row]  : row partials, one slot per (row, col-tile)
//   ws_col[(b*NT + rt)*PAD + col]  : col partials, one slot per (col, row-tile)
#define WSROW_F2 (GB * NT * PAD)     // 565504 float2

__device__ __forceinline__ float rot1(float x) {
    // rotate within 16-lane DPP row; full-rate VALU op, no LDS pipe
    return __int_as_float(__builtin_amdgcn_mov_dpp(
        __float_as_int(x), 0x121 /*row_ror:1*/, 0xF, 0xF, true));
}

__global__ __launch_bounds__(256) void geo_dpp_kernel(
    const float* __restrict__ p0,
    const float* __restrict__ p1,
    float* __restrict__ ws)
{
    const int lane = threadIdx.x & 63;
    const int wid  = (blockIdx.x << 2) | (threadIdx.x >> 6);   // 0..8835

    int b   = wid / TPB;
    int rem = wid - b * TPB;
    int rt  = rem / NT;
    int ct  = rem - rt * NT;

    const int r = (rt << 6) + lane;                // row this lane owns
    const int rload = (r < GN) ? r : (GN - 1);
    const float2 pr = ((const float2*)p0)[b * GN + rload];
    const float px2 = -2.0f * pr.x;
    const float py2 = -2.0f * pr.y;

    float rs = 0.0f, rc = 0.0f;

    float2* __restrict__ wrow = (float2*)ws + (b * NT + ct) * PAD;
    float2* __restrict__ wcol = (float2*)ws + WSROW_F2 + (b * NT + rt) * PAD;

    const bool full = (rt < NT - 1) && (ct < NT - 1);

    if (full) {
        #pragma unroll
        for (int g = 0; g < 4; ++g) {
            const int cidx = (ct << 6) + (g << 4) + (lane & 15);
            const float2 qq = ((const float2*)p1)[b * GN + cidx];
            float qx = qq.x, qy = qq.y;
            float cs = 0.0f, cc = 0.0f;
            #pragma unroll
            for (int j = 0; j < 16; ++j) {
                float t = fmaf(px2, qx, fmaf(py2, qy, 2.0f));
                t = fmaxf(t, 0.0f);
                float d = __builtin_amdgcn_sqrtf(t);
                float rr = d * INV2PI;
                float s = __builtin_amdgcn_sinf(rr);
                float c = __builtin_amdgcn_cosf(rr);
                rs += s;  rc += c;
                cs += s;  cc += c;
                qx = rot1(qx);  qy = rot1(qy);
                cs = rot1(cs);  cc = rot1(cc);
            }
            cs += __shfl_xor(cs, 16, 64);  cs += __shfl_xor(cs, 32, 64);
            cc += __shfl_xor(cc, 16, 64);  cc += __shfl_xor(cc, 32, 64);
            if (lane < 16)
                wcol[(ct << 6) + (g << 4) + lane] = make_float2(cs, cc);
        }
    } else {
        const float rowv = (r < GN) ? 1.0f : 0.0f;
        #pragma unroll
        for (int g = 0; g < 4; ++g) {
            const int cidx0 = (ct << 6) + (g << 4) + (lane & 15);
            const int cidx  = (cidx0 < GN) ? cidx0 : (GN - 1);
            const float2 qq = ((const float2*)p1)[b * GN + cidx];
            float qx = qq.x, qy = qq.y;
            float colv = (cidx0 < GN) ? 1.0f : 0.0f;
            float cs = 0.0f, cc = 0.0f;
            #pragma unroll
            for (int j = 0; j < 16; ++j) {
                float t = fmaf(px2, qx, fmaf(py2, qy, 2.0f));
                t = fmaxf(t, 0.0f);
                float d = __builtin_amdgcn_sqrtf(t);
                float rr = d * INV2PI;
                float s = __builtin_amdgcn_sinf(rr) * rowv;   // dead row -> 0
                float c = __builtin_amdgcn_cosf(rr) * rowv;
                rs = fmaf(s, colv, rs);                       // dead col -> 0
                rc = fmaf(c, colv, rc);
                cs += s;  cc += c;
                qx = rot1(qx);  qy = rot1(qy);
                cs = rot1(cs);  cc = rot1(cc);
                colv = rot1(colv);
            }
            cs += __shfl_xor(cs, 16, 64);  cs += __shfl_xor(cs, 32, 64);
            cc += __shfl_xor(cc, 16, 64);  cc += __shfl_xor(cc, 32, 64);
            if (lane < 16)
                wcol[(ct << 6) + (g << 4) + lane] = make_float2(cs, cc);
        }
    }

    wrow[r < PAD ? r : PAD - 1] = make_float2(rs, rc);   // r <= 3007 always
}

// Fused reduce + epilogue: out row i sums its 47 tile-partials, then * point.
__global__ __launch_bounds__(256) void geo_reduce_kernel(
    const float* __restrict__ p0,
    const float* __restrict__ p1,
    const float* __restrict__ ws,
    float* __restrict__ out)
{
    const int i = blockIdx.x * 256 + threadIdx.x;
    const int ROWS = GB * GN;                        // 12000 per side
    if (i >= 2 * ROWS) return;

    const bool side0 = (i < ROWS);
    const int idx = side0 ? i : i - ROWS;
    const int b = idx / GN;
    const int r = idx - b * GN;

    const float2* base = side0
        ? (const float2*)ws + (b * NT) * PAD + r
        : (const float2*)ws + WSROW_F2 + (b * NT) * PAD + r;

    float sx = 0.0f, sy = 0.0f;
    #pragma unroll 8
    for (int t = 0; t < NT; ++t) {
        float2 v = base[t * PAD];
        sx += v.x;
        sy += v.y;
    }

    const float2 p = side0 ? ((const float2*)p0)[idx]
                           : ((const float2*)p1)[idx];
    float2 res;
    res.x = p.x * sx;
    res.y = p.y * sy;
    ((float2*)out)[i] = res;
}

extern "C" void kernel_launch(void* const* d_in, const int* in_sizes, int n_in,
                              void* d_out, int out_size, void* d_ws, size_t ws_size,
                              hipStream_t stream) {
    const float* points0 = (const float*)d_in[0];
    const float* points1 = (const float*)d_in[1];
    float* out = (float*)d_out;
    float* ws = (float*)d_ws;

    // all ws slots we read are written unconditionally -> no memset needed
    const int nblocks = (GB * TPB + 3) / 4;          // 2209
    geo_dpp_kernel<<<dim3(nblocks), dim3(256), 0, stream>>>(points0, points1, ws);

    const int rows2 = 2 * GB * GN;                   // 24000
    geo_reduce_kernel<<<dim3((rows2 + 255) / 256), dim3(256), 0, stream>>>(
        points0, points1, ws, out);
}